// Round 20
// baseline (1648.140 us; speedup 1.0000x reference)
//
#include <hip/hip_runtime.h>
#include <hip/hip_bf16.h>

#define Vv 32000
#define Ee 256
#define Hh 256
#define Bb 32
#define TEe 128
#define TDd 64

typedef __attribute__((ext_vector_type(4))) float f32x4;
typedef __attribute__((ext_vector_type(8))) short short8;
typedef __attribute__((ext_vector_type(2))) unsigned int uint2v;
typedef __attribute__((ext_vector_type(4))) unsigned int uint4v;

static __device__ __forceinline__ unsigned short f2bf(float f){
  unsigned u = __float_as_uint(f);
  u += 0x7fffu + ((u >> 16) & 1u);           // round-to-nearest-even
  return (unsigned short)(u >> 16);
}
static __device__ __forceinline__ unsigned pack2(float a, float b){
  return ((unsigned)f2bf(b) << 16) | (unsigned)f2bf(a);
}
// dot of 8 packed bf16 (uint4) with 8 f32
static __device__ __forceinline__ float dot8(uint4v u, const float* hh){
  float s = 0.f;
  #pragma unroll
  for (int i = 0; i < 4; ++i){
    unsigned w = u[i];
    s = fmaf(__uint_as_float(w << 16),        hh[2*i],   s);
    s = fmaf(__uint_as_float(w & 0xffff0000u), hh[2*i+1], s);
  }
  return s;
}
static __device__ __forceinline__ float sigmoidf_(float x){
  return 1.f / (1.f + __expf(-x));
}
// async global->LDS 16B: wave-uniform LDS base, HW writes base + lane*16
static __device__ __forceinline__ void gload16(const void* g, void* l){
  __builtin_amdgcn_global_load_lds((const __attribute__((address_space(1))) void*)g,
                                   (__attribute__((address_space(3))) void*)l, 16, 0, 0);
}

// ---------------- fused prep: chunked Wh (f/b/d) + bf16 Wi_f/Wi_b/Wi_d + W2^T ----------------
__global__ void k_prep(const float* __restrict__ Wh_f, const float* __restrict__ Wh_b,
                       const float* __restrict__ Wh_d,
                       const float* __restrict__ Wi_f, const float* __restrict__ Wi_b,
                       const float* __restrict__ Wi_d, const float* __restrict__ W2_w,
                       unsigned short* __restrict__ whf, unsigned short* __restrict__ whb,
                       unsigned short* __restrict__ whd,
                       unsigned short* __restrict__ wif, unsigned short* __restrict__ wib,
                       unsigned short* __restrict__ wid, unsigned short* __restrict__ w2t){
  int idx = blockIdx.x * 256 + threadIdx.x;
  if (idx < 589824){                         // 3x chunked Wh [32][768][8]
    int which = idx / 196608, local = idx % 196608;
    int i = local & 7, r = (local >> 3) % 768, kb = local / 6144;
    const float* src = (which == 0) ? Wh_f : (which == 1) ? Wh_b : Wh_d;
    unsigned short* dst = (which == 0) ? whf : (which == 1) ? whb : whd;
    dst[local] = f2bf(src[(size_t)r*256 + kb*8 + i]);
  } else if (idx < 786432)   wif[idx - 589824] = f2bf(Wi_f[idx - 589824]);
  else if (idx < 983040)     wib[idx - 786432] = f2bf(Wi_b[idx - 786432]);
  else if (idx < 1572864)    wid[idx - 983040] = f2bf(Wi_d[idx - 983040]);
  else if (idx < 1703936){
    int l = idx - 1572864;                   // l = n*512 + k
    int n = l >> 9, k = l & 511;
    w2t[l] = f2bf(W2_w[k*256 + n]);          // W2_w is [512][256]
  }
}

// ---------------- bf16 MFMA GEMM: C[M,N] = A[M,K] * B^T + bias ----------------
// bf16 operands use global_load_lds(16B) staging into LINEAR [128][32] tiles;
// f32/gather operands use reg-staging into padded [128][40].
// OUTMODE: 0=f32, 1=bf16 row-major, 2=bf16 projt-chunked [B][16][768][8].
template<bool A_BF16, bool A_GATHER, bool B_BF16, int OUTMODE>
__global__ __launch_bounds__(256) void k_gemm(
  const void* __restrict__ Av, const int* __restrict__ tokp, const float* __restrict__ embp,
  const void* __restrict__ Bv,
  const float* __restrict__ bias, void* __restrict__ Cv,
  int M, int N, int K, int lda, int ldb, int ldc)
{
  __shared__ unsigned short lA[128*40];
  __shared__ unsigned short lB[128*40];
  const int SA = A_BF16 ? 32 : 40;
  const int SB = B_BF16 ? 32 : 40;
  const int tid  = threadIdx.x;
  const int lane = tid & 63;
  const int wvv  = tid >> 6;
  const int wr = wvv >> 1, wc = wvv & 1;
  const int m0 = blockIdx.y * 128, n0 = blockIdx.x * 128;
  f32x4 acc[4][4];
  #pragma unroll
  for (int i = 0; i < 4; ++i)
    #pragma unroll
    for (int j = 0; j < 4; ++j) acc[i][j] = (f32x4){0.f,0.f,0.f,0.f};

  for (int k0 = 0; k0 < K; k0 += 32){
    if (A_GATHER){
      #pragma unroll
      for (int it = 0; it < 4; ++it){
        int idx = tid + it*256; int r = idx >> 3, q = idx & 7;
        const float* src = embp + (size_t)tokp[m0 + r]*256 + k0 + q*4;
        f32x4 v = *(const f32x4*)src;
        uint2v pk; pk[0] = pack2(v[0], v[1]); pk[1] = pack2(v[2], v[3]);
        *(uint2v*)&lA[r*40 + q*4] = pk;
      }
    } else if (A_BF16){
      const unsigned short* A = (const unsigned short*)Av;
      #pragma unroll
      for (int i = 0; i < 2; ++i){
        const int rowb = (wvv*2 + i)*16;
        gload16(A + (size_t)(m0 + rowb + (lane >> 2))*lda + k0 + (lane & 3)*8,
                &lA[rowb*32]);
      }
    } else {
      const float* A = (const float*)Av;
      #pragma unroll
      for (int it = 0; it < 4; ++it){
        int idx = tid + it*256; int r = idx >> 3, q = idx & 7;
        f32x4 v = *(const f32x4*)(A + (size_t)(m0+r)*lda + k0 + q*4);
        uint2v pk; pk[0] = pack2(v[0], v[1]); pk[1] = pack2(v[2], v[3]);
        *(uint2v*)&lA[r*40 + q*4] = pk;
      }
    }
    if (B_BF16){
      const unsigned short* Bp = (const unsigned short*)Bv;
      #pragma unroll
      for (int i = 0; i < 2; ++i){
        const int rowb = (wvv*2 + i)*16;
        gload16(Bp + (size_t)(n0 + rowb + (lane >> 2))*ldb + k0 + (lane & 3)*8,
                &lB[rowb*32]);
      }
    } else {
      const float* Bp = (const float*)Bv;
      #pragma unroll
      for (int it = 0; it < 4; ++it){
        int idx = tid + it*256; int r = idx >> 3, q = idx & 7;
        f32x4 v = *(const f32x4*)(Bp + (size_t)(n0+r)*ldb + k0 + q*4);
        uint2v pk; pk[0] = pack2(v[0], v[1]); pk[1] = pack2(v[2], v[3]);
        *(uint2v*)&lB[r*40 + q*4] = pk;
      }
    }
    __syncthreads();
    short8 av[4], bv[4];
    #pragma unroll
    for (int i = 0; i < 4; ++i)
      av[i] = *(const short8*)&lA[(wr*64 + i*16 + (lane&15))*SA + (lane>>4)*8];
    #pragma unroll
    for (int j = 0; j < 4; ++j)
      bv[j] = *(const short8*)&lB[(wc*64 + j*16 + (lane&15))*SB + (lane>>4)*8];
    #pragma unroll
    for (int i = 0; i < 4; ++i)
      #pragma unroll
      for (int j = 0; j < 4; ++j)
        acc[i][j] = __builtin_amdgcn_mfma_f32_16x16x32_bf16(av[i], bv[j], acc[i][j], 0, 0, 0);
    __syncthreads();
  }
  #pragma unroll
  for (int i = 0; i < 4; ++i){
    #pragma unroll
    for (int j = 0; j < 4; ++j){
      int col = n0 + wc*64 + j*16 + (lane & 15);
      float bb = bias ? bias[col] : 0.f;
      #pragma unroll
      for (int r = 0; r < 4; ++r){
        int row = m0 + wr*64 + i*16 + (lane>>4)*4 + r;
        float v = acc[i][j][r] + bb;
        if (OUTMODE == 2){
          ((unsigned short*)Cv)[(size_t)(row >> 7)*98304 + (size_t)((row & 127) >> 3)*6144
                                + (size_t)col*8 + (row & 7)] = f2bf(v);
        } else if (OUTMODE == 1){
          ((unsigned short*)Cv)[(size_t)row*ldc + col] = f2bf(v);
        } else {
          ((float*)Cv)[(size_t)row*ldc + col] = v;
        }
      }
    }
  }
}

// ---------------- encoder superkernel: 192 blocks, 1024 threads ----------------
// Blocks 0-63:    recurrence (R16/R17/R18 measured-best form; 0 bank conflicts).
// Blocks 64-159:  folded gi_dx GEMM (independent of the recurrence; its old
//                 serial launch is removed). Barrier-uniform: all 1024 threads
//                 execute both __syncthreads per K-step; threads>=256 idle.
// Blocks 160-191: lin_w f32->bf16 conversion (hidden under the 850us encoder).
__global__ __launch_bounds__(1024) void k_encoder(
  const unsigned short* __restrict__ Whf, const unsigned short* __restrict__ Whb,
  const float* __restrict__ bhf, const float* __restrict__ bhb,
  const float* __restrict__ gif, const float* __restrict__ gib,
  float* __restrict__ encoded, unsigned short* __restrict__ encoded_bf,
  const float* __restrict__ lin_w, unsigned short* __restrict__ lin_bf, int do_lin,
  const int* __restrict__ dec_in, const float* __restrict__ embW,
  const unsigned short* __restrict__ wid_bf, const float* __restrict__ bi_d,
  float* __restrict__ gi_dx)
{
  extern __shared__ char smem[];
  if (blockIdx.x >= 160){
    if (do_lin){
      const int nlin = Vv*Hh;
      for (int i = (blockIdx.x - 160)*1024 + threadIdx.x; i < nlin; i += 32*1024)
        lin_bf[i] = f2bf(lin_w[i]);
    }
    return;
  }
  if (blockIdx.x >= 64){
    // folded gi_dx: C[2048,768] = gather(emb[dec_in]) @ (wid_bf+512)^T + bi_d
    unsigned short* lA = (unsigned short*)smem;             // 128*40 ushort
    unsigned short* lB = (unsigned short*)(smem + 16384);   // 128*32 ushort (linear)
    const int g = blockIdx.x - 64;
    const int m0 = (g & 15)*128, n0 = (g >> 4)*128;
    const int tid = threadIdx.x;
    const int lane = tid & 63, wvv = tid >> 6;
    const int wr = wvv >> 1, wc = wvv & 1;
    const unsigned short* Bp = wid_bf + 512;
    f32x4 acc[4][4];
    #pragma unroll
    for (int i = 0; i < 4; ++i)
      #pragma unroll
      for (int j = 0; j < 4; ++j) acc[i][j] = (f32x4){0.f,0.f,0.f,0.f};
    for (int k0 = 0; k0 < 256; k0 += 32){
      if (tid < 256){
        #pragma unroll
        for (int it = 0; it < 4; ++it){
          int idx = tid + it*256; int r = idx >> 3, q = idx & 7;
          const float* src = embW + (size_t)dec_in[m0 + r]*256 + k0 + q*4;
          f32x4 v = *(const f32x4*)src;
          uint2v pk; pk[0] = pack2(v[0], v[1]); pk[1] = pack2(v[2], v[3]);
          *(uint2v*)&lA[r*40 + q*4] = pk;
        }
        #pragma unroll
        for (int i = 0; i < 2; ++i){
          const int rowb = (wvv*2 + i)*16;
          gload16(Bp + (size_t)(n0 + rowb + (lane >> 2))*768 + k0 + (lane & 3)*8,
                  &lB[rowb*32]);
        }
      }
      __syncthreads();
      if (tid < 256){
        short8 av[4], bv[4];
        #pragma unroll
        for (int i = 0; i < 4; ++i)
          av[i] = *(const short8*)&lA[(wr*64 + i*16 + (lane&15))*40 + (lane>>4)*8];
        #pragma unroll
        for (int j = 0; j < 4; ++j)
          bv[j] = *(const short8*)&lB[(wc*64 + j*16 + (lane&15))*32 + (lane>>4)*8];
        #pragma unroll
        for (int i = 0; i < 4; ++i)
          #pragma unroll
          for (int j = 0; j < 4; ++j)
            acc[i][j] = __builtin_amdgcn_mfma_f32_16x16x32_bf16(av[i], bv[j], acc[i][j], 0, 0, 0);
      }
      __syncthreads();
    }
    if (tid < 256){
      #pragma unroll
      for (int i = 0; i < 4; ++i){
        #pragma unroll
        for (int j = 0; j < 4; ++j){
          int col = n0 + wc*64 + j*16 + (lane & 15);
          float bb = bi_d[col];
          #pragma unroll
          for (int r = 0; r < 4; ++r){
            int row = m0 + wr*64 + i*16 + (lane>>4)*4 + r;
            gi_dx[(size_t)row*768 + col] = acc[i][j][r] + bb;
          }
        }
      }
    }
    return;
  }
  // ---- recurrence (R16/R17/R18 measured-best) ----
  unsigned short* lw = (unsigned short*)smem;        // 131072
  float* hA   = (float*)(smem + 131072);             // 1024
  float* hB   = (float*)(smem + 132096);             // 1024
  float* parA = (float*)(smem + 133120);             // 4096
  float* parB = (float*)(smem + 137216);             // 4096 -> total 141312
  const int dir = blockIdx.x & 1, b = blockIdx.x >> 1;
  const unsigned short* Wh = dir ? Whb : Whf;
  const float* bh = dir ? bhb : bhf;
  const float* gi = dir ? gib : gif;
  const int T = threadIdx.x;
  const int rl = T & 255, q4 = T >> 8;
  const int rrh = T & 511, hf = T >> 9;
  const unsigned short* wsrc = Wh + (size_t)(hf*16)*6144 + (size_t)(256 + rrh)*8;
  uint4v wb[8];
  #pragma unroll
  for (int d = 0; d < 8; ++d) wb[d] = *(const uint4v*)(wsrc + (size_t)d*6144);
  for (int cc = T; cc < 256*32; cc += 1024){
    int r = cc >> 5, q = cc & 31;
    *(uint4v*)&lw[(r*32 + (q ^ (r & 31)))*8] = *(const uint4v*)(Wh + (size_t)q*6144 + r*8);
  }
  float bh0 = 0.f, bh1 = 0.f, bh2 = 0.f;
  if (T < 256){ bh0 = bh[T]; bh1 = bh[T+256]; bh2 = bh[T+512]; hA[T] = 0.f; }
  __syncthreads();
  const float* hc = hA; float* hn = hB;
  for (int s = 0; s < TEe; ++s){
    const int t = dir ? (TEe-1-s) : s;
    float g0 = 0.f, g1 = 0.f, g2 = 0.f;
    if (T < 256){
      const float* grow = gi + (size_t)(b*TEe + t)*768;
      g0 = grow[T]; g1 = grow[T+256]; g2 = grow[T+512];
    }
    // LDS-part: quarter q4 of row rl
    float aL = 0.f;
    #pragma unroll
    for (int i = 0; i < 8; ++i){
      const int ck = q4*8 + i;
      float hr[8];
      *(f32x4*)&hr[0] = *(const f32x4*)&hc[ck*8];
      *(f32x4*)&hr[4] = *(const f32x4*)&hc[ck*8+4];
      aL += dot8(*(const uint4v*)&lw[(rl*32 + (ck ^ (rl & 31)))*8], hr);
    }
    parA[q4*256 + rl] = aL;
    // stream-part: half hf of row 256+rrh, depth-8 ring
    float aR = 0.f;
    const float* hh = hc + hf*128;
    #pragma unroll
    for (int q = 0; q < 16; ++q){
      float hr[8];
      *(f32x4*)&hr[0] = *(const f32x4*)&hh[q*8];
      *(f32x4*)&hr[4] = *(const f32x4*)&hh[q*8+4];
      aR += dot8(wb[q & 7], hr);
      wb[q & 7] = *(const uint4v*)(wsrc + (size_t)((q < 8) ? (q + 8) : (q - 8))*6144);
    }
    parB[hf*512 + rrh] = aR;
    __syncthreads();                   // B1: partials ready
    if (T < 256){
      const int j = T;
      const float A0 = parA[j] + parA[256+j] + parA[512+j] + parA[768+j] + bh0;
      const float A1 = parB[j] + parB[512+j] + bh1;
      const float A2 = parB[256+j] + parB[768+j] + bh2;
      const float r = sigmoidf_(g0 + A0);
      const float z = sigmoidf_(g1 + A1);
      const float n = tanhf(g2 + r*A2);
      const float hnew = (1.f - z)*n + z*hc[j];
      hn[j] = hnew;
      const size_t off = (size_t)(b*TEe + t)*512 + dir*256 + j;
      encoded[off] = hnew;
      encoded_bf[off] = f2bf(hnew);
    }
    __syncthreads();                   // B2: h_new visible
    const float* tmp = hc; hc = hn; hn = (float*)tmp;
  }
}

// ---------------- fused post: encb2 (blocks 0-1023) + sizes+hinit (1024-1055) ----------------
__global__ __launch_bounds__(256) void k_post(
  const float* __restrict__ encoded, const float* __restrict__ W2b, float* __restrict__ encb2,
  const int* __restrict__ enc_in, const float* __restrict__ W1w, const float* __restrict__ W1b,
  float* __restrict__ h0)
{
  if (blockIdx.x < 1024){
    const int r = blockIdx.x*4 + (threadIdx.x >> 6), l = threadIdx.x & 63;
    const float* e = encoded + (size_t)r*512;
    float s = 0.f;
    for (int k = l; k < 512; k += 64) s += e[k]*W2b[k];
    for (int off = 32; off; off >>= 1) s += __shfl_down(s, off);
    if (l == 0) encb2[r] = s;
  } else {
    const int b = blockIdx.x - 1024, o = threadIdx.x;
    int c = 0;
    for (int t = 0; t < TEe; ++t) c += (enc_in[b*TEe + t] > 0);
    int idx = c - 1;
    idx = idx < 0 ? 0 : (idx > TEe-1 ? TEe-1 : idx);
    const float* ls = encoded + (size_t)(b*TEe + idx)*512;
    const float* wv = W1w + (size_t)o*512;
    float s = W1b[o];
    for (int k = 0; k < 512; k += 4){
      f32x4 a = *(const f32x4*)(ls + k);
      f32x4 w4 = *(const f32x4*)(wv + k);
      s = fmaf(a[0],w4[0], fmaf(a[1],w4[1], fmaf(a[2],w4[2], fmaf(a[3],w4[3], s))));
    }
    h0[b*256 + o] = s;
  }
}

// ---------------- decoder: 32 blocks = batch, 512 threads ----------------
// R12 version (unchanged, measured ~325us): 128-VGPR cap, persistent rings.
// n-gate: ctx (gc) stays OUTSIDE the r* product; bh_n INSIDE (ref semantics).
#define DLR 128
__global__ __launch_bounds__(512, 1) void k_decoder(
  const unsigned short* __restrict__ Whd, const float* __restrict__ bhd,
  const float* __restrict__ gidx,            // [B][TD][768] f32 (includes bi_d)
  const unsigned short* __restrict__ encw2,  // [B*TE][256] bf16
  const float* __restrict__ encb2,           // [B*TE]
  const unsigned short* __restrict__ projt,  // [B][16][768][8] bf16
  const float* __restrict__ h0,
  unsigned short* __restrict__ outs_bf)      // [B][TD][256] bf16
{
  extern __shared__ char smem[];
  unsigned short* le = (unsigned short*)smem;            // 65536
  unsigned short* lw = (unsigned short*)(smem + 65536);  // DLR*512 = 65536
  float* h    = (float*)(smem + 131072);                 // 1024
  float* parL = (float*)(smem + 132096);                 // 2048 (4 quarters x 128)
  float* parS1= (float*)(smem + 134144);                 // 2048 (rows 128-639)
  float* parS2= (float*)(smem + 136192);                 // 2048 (4 quarters x 128, rows 640-767)
  float* gcs  = (float*)(smem + 138240);                 // 2048 (ctx rows 0-511)
  float* cpar = (float*)(smem + 140288);                 // 2048 (2 halves x 256, ctx rows 512-767)
  float* p    = (float*)(smem + 142336);                 // 512
  float* ebl  = (float*)(smem + 142848);                 // 512 -> total 143360
  const int b = blockIdx.x, T = threadIdx.x;             // [0,512)
  const unsigned short* ptc = projt + (size_t)b*98304;
  const unsigned short* wsrcM = Whd + (size_t)(DLR + T)*8;     // rows 128..639
  const int trow = 640 + (T >> 2), tq = (T & 3)*8;             // rows 640..767
  const unsigned short* wsrcT = Whd + (size_t)trow*8;
  const unsigned short* csrcM = ptc + (size_t)T*8;             // ctx rows 0..511
  const int crow = 512 + (T >> 1), cq = (T & 1)*8;             // ctx rows 512..767
  const unsigned short* csrcT = ptc + (size_t)crow*8;
  uint4v wb[8], wb2[2], cb[4], cb2[2];
  #pragma unroll
  for (int d = 0; d < 8; ++d) wb[d] = *(const uint4v*)(wsrcM + (size_t)d*6144);
  wb2[0] = *(const uint4v*)(wsrcT + (size_t)tq*6144);
  wb2[1] = *(const uint4v*)(wsrcT + (size_t)(tq+1)*6144);
  #pragma unroll
  for (int d = 0; d < 4; ++d) cb[d] = *(const uint4v*)(csrcM + (size_t)d*6144);
  cb2[0] = *(const uint4v*)(csrcT + (size_t)cq*6144);
  cb2[1] = *(const uint4v*)(csrcT + (size_t)(cq+1)*6144);
  for (int cc = T; cc < 128*32; cc += 512){
    int r = cc >> 5, q = cc & 31;
    *(uint4v*)&le[(r*32 + (q ^ (r & 31)))*8] =
        *(const uint4v*)(encw2 + ((size_t)(b*TEe + r) << 8) + (q << 3));
  }
  for (int cc = T; cc < DLR*32; cc += 512){
    int r = cc >> 5, q = cc & 31;
    *(uint4v*)&lw[(r*32 + (q ^ (r & 31)))*8] =
        *(const uint4v*)(Whd + (size_t)q*6144 + r*8);
  }
  for (int i = T; i < 256; i += 512) h[i] = h0[b*256 + i];
  gcs[T] = 0.f; cpar[T] = 0.f;                           // ctx_init = 0
  if (T < TEe) ebl[T] = encb2[b*TEe + T];
  float bh0 = 0.f, bh1 = 0.f, bh2 = 0.f;
  if (T < 256){ bh0 = bhd[T]; bh1 = bhd[T+256]; bh2 = bhd[T+512]; }
  __syncthreads();
  float g0 = 0.f, g1 = 0.f, g2 = 0.f;
  if (T < 256){
    const float* grow = gidx + (size_t)(b*TDd)*768;
    g0 = grow[T]; g1 = grow[T+256]; g2 = grow[T+512];
  }
  #define DOTS_BODY                                                            \
  {                                                                            \
    { const int rL2 = T >> 2, qb2 = (T & 3)*8;                                 \
      const unsigned short* lwr = lw + rL2*256;                                \
      float a = 0.f;                                                           \
      _Pragma("unroll")                                                        \
      for (int i = 0; i < 8; ++i){                                             \
        const int q = qb2 + i;                                                 \
        float hr[8];                                                           \
        *(f32x4*)&hr[0] = *(const f32x4*)&h[q*8];                              \
        *(f32x4*)&hr[4] = *(const f32x4*)&h[q*8+4];                            \
        a += dot8(*(const uint4v*)(lwr + ((q ^ (rL2 & 31)) << 3)), hr);        \
      }                                                                        \
      parL[(T & 3)*128 + rL2] = a;                                             \
    }                                                                          \
    { float a = 0.f;                                                           \
      _Pragma("unroll")                                                        \
      for (int q = 0; q < 32; ++q){                                            \
        float hr[8];                                                           \
        *(f32x4*)&hr[0] = *(const f32x4*)&h[q*8];                              \
        *(f32x4*)&hr[4] = *(const f32x4*)&h[q*8+4];                            \
        a += dot8(wb[q & 7], hr);                                              \
        wb[q & 7] = *(const uint4v*)(wsrcM + (size_t)((q < 24) ? (q + 8) : (q - 24))*6144); \
      }                                                                        \
      parS1[T] = a;                                                            \
    }                                                                          \
    { float a = 0.f;                                                           \
      _Pragma("unroll")                                                        \
      for (int i = 0; i < 8; ++i){                                             \
        const int q = tq + i;                                                  \
        float hr[8];                                                           \
        *(f32x4*)&hr[0] = *(const f32x4*)&h[q*8];                              \
        *(f32x4*)&hr[4] = *(const f32x4*)&h[q*8+4];                            \
        a += dot8(wb2[i & 1], hr);                                             \
        wb2[i & 1] = *(const uint4v*)(wsrcT + (size_t)(tq + ((i < 6) ? (i + 2) : (i - 6)))*6144); \
      }                                                                        \
      parS2[(T & 3)*128 + (T >> 2)] = a;                                       \
    }                                                                          \
  }
  DOTS_BODY
  __syncthreads();
  for (int t = 0; t < TDd; ++t){
    if (T < 256){
      const int j = T;
      float A0, A2;
      if (j < 128){
        A0 = parL[j] + parL[128+j] + parL[256+j] + parL[384+j];
        A2 = parS1[384+j];
      } else {
        A0 = parS1[j-128];
        A2 = parS2[j-128] + parS2[j] + parS2[j+128] + parS2[j+256];
      }
      const float A1 = parS1[128+j];
      const float gcr = gcs[j];
      const float gcz = gcs[256+j];
      const float gcn = cpar[j] + cpar[256+j];
      const float r = sigmoidf_(g0 + gcr + A0 + bh0);
      const float z = sigmoidf_(g1 + gcz + A1 + bh1);
      const float n = tanhf(g2 + gcn + r*(A2 + bh2));
      const float hnew = (1.f - z)*n + z*h[j];
      h[j] = hnew;
      outs_bf[(size_t)(b*TDd + t)*256 + j] = f2bf(hnew);
    }
    if (t + 1 == TDd) break;
    __syncthreads();                   // B1: h_t visible
    if (T < 256){
      const float* grow = gidx + (size_t)(b*TDd + t + 1)*768;
      g0 = grow[T]; g1 = grow[T+256]; g2 = grow[T+512];
    }
    DOTS_BODY
    {
      const int pos = T >> 2, kq = (T & 3)*8;
      const unsigned short* er = le + pos*256;
      float s = 0.f;
      #pragma unroll
      for (int i = 0; i < 8; ++i){
        const int q = kq + i;
        float hr[8];
        *(f32x4*)&hr[0] = *(const f32x4*)&h[q*8];
        *(f32x4*)&hr[4] = *(const f32x4*)&h[q*8+4];
        s += dot8(*(const uint4v*)(er + ((q ^ (pos & 31)) << 3)), hr);
      }
      s += __shfl_xor(s, 1);
      s += __shfl_xor(s, 2);
      if ((T & 3) == 0) p[pos] = s + ebl[pos];
    }
    __syncthreads();                   // B2: raw scores ready
    if (T < 64){
      float m = fmaxf(p[T], p[T+64]);
      for (int off = 32; off; off >>= 1) m = fmaxf(m, __shfl_xor(m, off));
      float e0 = __expf(p[T] - m), e1 = __expf(p[T+64] - m);
      float ss = e0 + e1;
      for (int off = 32; off; off >>= 1) ss += __shfl_xor(ss, off);
      float inv = 1.f / ss;
      p[T] = e0*inv; p[T+64] = e1*inv;
    }
    __syncthreads();                   // B3: softmax done
    {
      float c = 0.f;
      #pragma unroll
      for (int q = 0; q < 16; ++q){
        float pr[8];
        *(f32x4*)&pr[0] = *(const f32x4*)&p[q*8];
        *(f32x4*)&pr[4] = *(const f32x4*)&p[q*8+4];
        c += dot8(cb[q & 3], pr);
        cb[q & 3] = *(const uint4v*)(csrcM + (size_t)((q < 12) ? (q + 4) : (q - 12))*6144);
      }
      gcs[T] = c;
      float c2 = 0.f;
      #pragma unroll
      for (int i = 0; i < 8; ++i){
        const int q = cq + i;
        float pr[8];
        *(f32x4*)&pr[0] = *(const f32x4*)&p[q*8];
        *(f32x4*)&pr[4] = *(const f32x4*)&p[q*8+4];
        c2 += dot8(cb2[i & 1], pr);
        cb2[i & 1] = *(const uint4v*)(csrcT + (size_t)(cq + ((i < 6) ? (i + 2) : (i - 6)))*6144);
      }
      cpar[(T & 1)*256 + (T >> 1)] = c2;
    }
    __syncthreads();                   // B4: gcs/cpar ready for next gates
  }
  #undef DOTS_BODY
}

extern "C" void kernel_launch(void* const* d_in, const int* in_sizes, int n_in,
                              void* d_out, int out_size, void* d_ws, size_t ws_size,
                              hipStream_t stream)
{
  (void)in_sizes; (void)n_in; (void)out_size;
  const int*   enc_in = (const int*)d_in[0];
  const int*   dec_in = (const int*)d_in[1];
  const float* embW   = (const float*)d_in[2];
  const float* Wi_f   = (const float*)d_in[3];
  const float* Wh_f   = (const float*)d_in[4];
  const float* bi_f   = (const float*)d_in[5];
  const float* bh_f   = (const float*)d_in[6];
  const float* Wi_b   = (const float*)d_in[7];
  const float* Wh_b   = (const float*)d_in[8];
  const float* bi_b   = (const float*)d_in[9];
  const float* bh_b   = (const float*)d_in[10];
  const float* Wi_d   = (const float*)d_in[11];
  const float* Wh_d   = (const float*)d_in[12];
  const float* bi_d   = (const float*)d_in[13];
  const float* bh_d   = (const float*)d_in[14];
  const float* W1_w   = (const float*)d_in[15];
  const float* W1_b   = (const float*)d_in[16];
  const float* W2_w   = (const float*)d_in[17];
  const float* W2_b   = (const float*)d_in[18];
  const float* lin_w  = (const float*)d_in[19];
  const float* lin_b  = (const float*)d_in[20];

  // d_out (262 MB) doubles as scratch; all regions dead before final GEMM.
  char* scr = (char*)d_out;
  float* gi_f    = (float*)(scr + 3145728);                     // 12,582,912
  float* gi_b    = (float*)(scr + 15728640);                    // 12,582,912
  float* gi_dx   = (float*)(scr + 28311552);                    //  6,291,456
  float* enc     = (float*)(scr + 34603008);                    //  8,388,608
  unsigned short* enc_bf  = (unsigned short*)(scr + 42991616);  //  4,194,304
  unsigned short* whf_bf = (unsigned short*)(scr + 53477376);   //    393,216
  unsigned short* whb_bf = (unsigned short*)(scr + 53870592);
  unsigned short* whd_bf = (unsigned short*)(scr + 54263808);
  unsigned short* encw2  = (unsigned short*)(scr + 54657024);   //  2,097,152
  unsigned short* projt  = (unsigned short*)(scr + 56754176);   //  6,291,456
  unsigned short* wif_bf = (unsigned short*)(scr + 63045632);   //    393,216
  unsigned short* wib_bf = (unsigned short*)(scr + 63438848);
  unsigned short* wid_bf = (unsigned short*)(scr + 63832064);   //  1,179,648
  unsigned short* w2t_bf = (unsigned short*)(scr + 65011712);   //    262,144
  float* encb2 = (float*)(scr + 65273856);
  float* h0    = (float*)(scr + 65290368);

  unsigned short* outs_bf = (unsigned short*)d_ws;
  unsigned short* lin_bf  = (unsigned short*)((char*)d_ws + (1<<20));
  const bool big = ws_size >= (size_t)(1<<20) + 16384000u + 1024u;

  hipFuncSetAttribute((const void*)k_encoder, hipFuncAttributeMaxDynamicSharedMemorySize, 141312);
  hipFuncSetAttribute((const void*)k_decoder, hipFuncAttributeMaxDynamicSharedMemorySize, 143360);

  // fused prep (weights -> chunked/bf16/transposed)
  k_prep<<<6656, 256, 0, stream>>>(Wh_f, Wh_b, Wh_d, Wi_f, Wi_b, Wi_d, W2_w,
                                   whf_bf, whb_bf, whd_bf, wif_bf, wib_bf, wid_bf, w2t_bf);

  // encoder input projections with fused embedding gather
  k_gemm<false,true,true,0><<<dim3(6,32), 256, 0, stream>>>(
      nullptr, enc_in, embW, wif_bf, bi_f, gi_f, 4096, 768, 256, 0, 256, 768);
  k_gemm<false,true,true,0><<<dim3(6,32), 256, 0, stream>>>(
      nullptr, enc_in, embW, wib_bf, bi_b, gi_b, 4096, 768, 256, 0, 256, 768);

  // encoder superkernel: recurrence + folded gi_dx GEMM + folded lin_w convert
  k_encoder<<<192, 1024, 141312, stream>>>(whf_bf, whb_bf, bh_f, bh_b, gi_f, gi_b,
                                           enc, enc_bf, lin_w, lin_bf, big ? 1 : 0,
                                           dec_in, embW, wid_bf, bi_d, gi_dx);
  // fused encb2 + sizes + hinit
  k_post<<<1056, 256, 0, stream>>>(enc, W2_b, encb2, enc_in, W1_w, W1_b, h0);

  // ENC_W2 = enc @ W2 (both operands via global_load_lds)
  k_gemm<true,false,true,1><<<dim3(2,32), 256, 0, stream>>>(
      enc_bf, nullptr, nullptr, w2t_bf, nullptr, encw2, 4096, 256, 512, 512, 512, 256);
  // ENC_PROJ = enc @ Wi_ctx^T, written directly in projt-chunked layout
  k_gemm<true,false,true,2><<<dim3(6,32), 256, 0, stream>>>(
      enc_bf, nullptr, nullptr, wid_bf, nullptr, projt, 4096, 768, 512, 512, 768, 0);

  k_decoder<<<Bb, 512, 143360, stream>>>(whd_bf, bh_d, gi_dx, encw2, encb2, projt, h0, outs_bf);

  if (big)
    k_gemm<true,false,true,0><<<dim3(250,16), 256, 0, stream>>>(
        outs_bf, nullptr, nullptr, lin_bf, lin_b, d_out, 2048, 32000, 256, 256, 256, 32000);
  else
    k_gemm<true,false,false,0><<<dim3(250,16), 256, 0, stream>>>(
        outs_bf, nullptr, nullptr, lin_w, lin_b, d_out, 2048, 32000, 256, 256, 256, 32000);
}

// Round 21
// 1623.216 us; speedup vs baseline: 1.0154x; 1.0154x over previous
//
#include <hip/hip_runtime.h>
#include <hip/hip_bf16.h>

#define Vv 32000
#define Ee 256
#define Hh 256
#define Bb 32
#define TEe 128
#define TDd 64

typedef __attribute__((ext_vector_type(4))) float f32x4;
typedef __attribute__((ext_vector_type(8))) short short8;
typedef __attribute__((ext_vector_type(2))) unsigned int uint2v;
typedef __attribute__((ext_vector_type(4))) unsigned int uint4v;

static __device__ __forceinline__ unsigned short f2bf(float f){
  unsigned u = __float_as_uint(f);
  u += 0x7fffu + ((u >> 16) & 1u);           // round-to-nearest-even
  return (unsigned short)(u >> 16);
}
static __device__ __forceinline__ unsigned pack2(float a, float b){
  return ((unsigned)f2bf(b) << 16) | (unsigned)f2bf(a);
}
// dot of 8 packed bf16 (uint4) with 8 f32
static __device__ __forceinline__ float dot8(uint4v u, const float* hh){
  float s = 0.f;
  #pragma unroll
  for (int i = 0; i < 4; ++i){
    unsigned w = u[i];
    s = fmaf(__uint_as_float(w << 16),        hh[2*i],   s);
    s = fmaf(__uint_as_float(w & 0xffff0000u), hh[2*i+1], s);
  }
  return s;
}
static __device__ __forceinline__ float sigmoidf_(float x){
  return 1.f / (1.f + __expf(-x));
}

// ---------------- fused prep: chunked Wh (f/b/d) + bf16 Wi_f/Wi_b/Wi_d + W2^T ----------------
__global__ void k_prep(const float* __restrict__ Wh_f, const float* __restrict__ Wh_b,
                       const float* __restrict__ Wh_d,
                       const float* __restrict__ Wi_f, const float* __restrict__ Wi_b,
                       const float* __restrict__ Wi_d, const float* __restrict__ W2_w,
                       unsigned short* __restrict__ whf, unsigned short* __restrict__ whb,
                       unsigned short* __restrict__ whd,
                       unsigned short* __restrict__ wif, unsigned short* __restrict__ wib,
                       unsigned short* __restrict__ wid, unsigned short* __restrict__ w2t){
  int idx = blockIdx.x * 256 + threadIdx.x;
  if (idx < 589824){                         // 3x chunked Wh [32][768][8]
    int which = idx / 196608, local = idx % 196608;
    int i = local & 7, r = (local >> 3) % 768, kb = local / 6144;
    const float* src = (which == 0) ? Wh_f : (which == 1) ? Wh_b : Wh_d;
    unsigned short* dst = (which == 0) ? whf : (which == 1) ? whb : whd;
    dst[local] = f2bf(src[(size_t)r*256 + kb*8 + i]);
  } else if (idx < 786432)   wif[idx - 589824] = f2bf(Wi_f[idx - 589824]);
  else if (idx < 983040)     wib[idx - 786432] = f2bf(Wi_b[idx - 786432]);
  else if (idx < 1572864)    wid[idx - 983040] = f2bf(Wi_d[idx - 983040]);
  else if (idx < 1703936){
    int l = idx - 1572864;                   // l = n*512 + k
    int n = l >> 9, k = l & 511;
    w2t[l] = f2bf(W2_w[k*256 + n]);          // W2_w is [512][256]
  }
}

// ---------------- bf16 MFMA GEMM: C[M,N] = A[M,K] * B^T + bias ----------------
// A_GATHER: A row m = embW[tok[m]] (f32, packed to bf16 in staging — identical
// rounding to the old gather-then-GEMM path). OUTMODE: 0=f32, 1=bf16 row-major,
// 2=bf16 projt-chunked [B][16][768][8].
template<bool A_BF16, bool A_GATHER, bool B_BF16, int OUTMODE>
__global__ __launch_bounds__(256) void k_gemm(
  const void* __restrict__ Av, const int* __restrict__ tokp, const float* __restrict__ embp,
  const void* __restrict__ Bv,
  const float* __restrict__ bias, void* __restrict__ Cv,
  int M, int N, int K, int lda, int ldb, int ldc)
{
  __shared__ unsigned short lA[128*40];
  __shared__ unsigned short lB[128*40];
  const int tid  = threadIdx.x;
  const int lane = tid & 63;
  const int w = tid >> 6, wr = w >> 1, wc = w & 1;
  const int m0 = blockIdx.y * 128, n0 = blockIdx.x * 128;
  f32x4 acc[4][4];
  #pragma unroll
  for (int i = 0; i < 4; ++i)
    #pragma unroll
    for (int j = 0; j < 4; ++j) acc[i][j] = (f32x4){0.f,0.f,0.f,0.f};

  for (int k0 = 0; k0 < K; k0 += 32){
    if (A_GATHER){
      #pragma unroll
      for (int it = 0; it < 4; ++it){
        int idx = tid + it*256; int r = idx >> 3, q = idx & 7;
        const float* src = embp + (size_t)tokp[m0 + r]*256 + k0 + q*4;
        f32x4 v = *(const f32x4*)src;
        uint2v pk; pk[0] = pack2(v[0], v[1]); pk[1] = pack2(v[2], v[3]);
        *(uint2v*)&lA[r*40 + q*4] = pk;
      }
    } else if (A_BF16){
      const unsigned short* A = (const unsigned short*)Av;
      #pragma unroll
      for (int it = 0; it < 2; ++it){
        int idx = tid + it*256; int r = idx >> 2, q = idx & 3;
        *(uint4v*)&lA[r*40 + q*8] = *(const uint4v*)(A + (size_t)(m0+r)*lda + k0 + q*8);
      }
    } else {
      const float* A = (const float*)Av;
      #pragma unroll
      for (int it = 0; it < 4; ++it){
        int idx = tid + it*256; int r = idx >> 3, q = idx & 7;
        f32x4 v = *(const f32x4*)(A + (size_t)(m0+r)*lda + k0 + q*4);
        uint2v pk; pk[0] = pack2(v[0], v[1]); pk[1] = pack2(v[2], v[3]);
        *(uint2v*)&lA[r*40 + q*4] = pk;
      }
    }
    if (B_BF16){
      const unsigned short* Bp = (const unsigned short*)Bv;
      #pragma unroll
      for (int it = 0; it < 2; ++it){
        int idx = tid + it*256; int r = idx >> 2, q = idx & 3;
        *(uint4v*)&lB[r*40 + q*8] = *(const uint4v*)(Bp + (size_t)(n0+r)*ldb + k0 + q*8);
      }
    } else {
      const float* Bp = (const float*)Bv;
      #pragma unroll
      for (int it = 0; it < 4; ++it){
        int idx = tid + it*256; int r = idx >> 3, q = idx & 7;
        f32x4 v = *(const f32x4*)(Bp + (size_t)(n0+r)*ldb + k0 + q*4);
        uint2v pk; pk[0] = pack2(v[0], v[1]); pk[1] = pack2(v[2], v[3]);
        *(uint2v*)&lB[r*40 + q*4] = pk;
      }
    }
    __syncthreads();
    short8 av[4], bv[4];
    #pragma unroll
    for (int i = 0; i < 4; ++i)
      av[i] = *(const short8*)&lA[(wr*64 + i*16 + (lane&15))*40 + (lane>>4)*8];
    #pragma unroll
    for (int j = 0; j < 4; ++j)
      bv[j] = *(const short8*)&lB[(wc*64 + j*16 + (lane&15))*40 + (lane>>4)*8];
    #pragma unroll
    for (int i = 0; i < 4; ++i)
      #pragma unroll
      for (int j = 0; j < 4; ++j)
        acc[i][j] = __builtin_amdgcn_mfma_f32_16x16x32_bf16(av[i], bv[j], acc[i][j], 0, 0, 0);
    __syncthreads();
  }
  #pragma unroll
  for (int i = 0; i < 4; ++i){
    #pragma unroll
    for (int j = 0; j < 4; ++j){
      int col = n0 + wc*64 + j*16 + (lane & 15);
      float bb = bias ? bias[col] : 0.f;
      #pragma unroll
      for (int r = 0; r < 4; ++r){
        int row = m0 + wr*64 + i*16 + (lane>>4)*4 + r;
        float v = acc[i][j][r] + bb;
        if (OUTMODE == 2){
          ((unsigned short*)Cv)[(size_t)(row >> 7)*98304 + (size_t)((row & 127) >> 3)*6144
                                + (size_t)col*8 + (row & 7)] = f2bf(v);
        } else if (OUTMODE == 1){
          ((unsigned short*)Cv)[(size_t)row*ldc + col] = f2bf(v);
        } else {
          ((float*)Cv)[(size_t)row*ldc + col] = v;
        }
      }
    }
  }
}

// ---------------- encoder: 64+128 blocks, 1024 threads ----------------
// Blocks 0-63: R13/R16 recurrence (0 bank conflicts): rows 0-255 LDS
// quarter-split; rows 256-767 streamed half-rows w/ depth-8 ring; gi rows
// PREFETCHED into registers before the dots (off the barrier-gated path).
// Blocks 64-191: lin_w f32->bf16 conversion on otherwise-idle CUs.
__global__ __launch_bounds__(1024) void k_encoder(
  const unsigned short* __restrict__ Whf, const unsigned short* __restrict__ Whb,
  const float* __restrict__ bhf, const float* __restrict__ bhb,
  const float* __restrict__ gif, const float* __restrict__ gib,
  float* __restrict__ encoded, unsigned short* __restrict__ encoded_bf,
  const float* __restrict__ lin_w, unsigned short* __restrict__ lin_bf, int do_lin)
{
  if (blockIdx.x >= 64){
    if (do_lin){
      const int nlin = Vv*Hh;
      for (int i = (blockIdx.x - 64)*1024 + threadIdx.x; i < nlin; i += 128*1024)
        lin_bf[i] = f2bf(lin_w[i]);
    }
    return;
  }
  extern __shared__ char smem[];
  unsigned short* lw = (unsigned short*)smem;        // 131072
  float* hA   = (float*)(smem + 131072);             // 1024
  float* hB   = (float*)(smem + 132096);             // 1024
  float* parA = (float*)(smem + 133120);             // 4096
  float* parB = (float*)(smem + 137216);             // 4096 -> total 141312
  const int dir = blockIdx.x & 1, b = blockIdx.x >> 1;
  const unsigned short* Wh = dir ? Whb : Whf;
  const float* bh = dir ? bhb : bhf;
  const float* gi = dir ? gib : gif;
  const int T = threadIdx.x;
  const int rl = T & 255, q4 = T >> 8;
  const int rrh = T & 511, hf = T >> 9;
  const unsigned short* wsrc = Wh + (size_t)(hf*16)*6144 + (size_t)(256 + rrh)*8;
  uint4v wb[8];
  #pragma unroll
  for (int d = 0; d < 8; ++d) wb[d] = *(const uint4v*)(wsrc + (size_t)d*6144);
  for (int cc = T; cc < 256*32; cc += 1024){
    int r = cc >> 5, q = cc & 31;
    *(uint4v*)&lw[(r*32 + (q ^ (r & 31)))*8] = *(const uint4v*)(Wh + (size_t)q*6144 + r*8);
  }
  float bh0 = 0.f, bh1 = 0.f, bh2 = 0.f;
  if (T < 256){ bh0 = bh[T]; bh1 = bh[T+256]; bh2 = bh[T+512]; hA[T] = 0.f; }
  __syncthreads();
  const float* hc = hA; float* hn = hB;
  for (int s = 0; s < TEe; ++s){
    const int t = dir ? (TEe-1-s) : s;
    // gi prefetch (t-dependent only; issued before dots so latency hides)
    float g0 = 0.f, g1 = 0.f, g2 = 0.f;
    if (T < 256){
      const float* grow = gi + (size_t)(b*TEe + t)*768;
      g0 = grow[T]; g1 = grow[T+256]; g2 = grow[T+512];
    }
    // LDS-part: quarter q4 of row rl
    float aL = 0.f;
    #pragma unroll
    for (int i = 0; i < 8; ++i){
      const int ck = q4*8 + i;
      float hr[8];
      *(f32x4*)&hr[0] = *(const f32x4*)&hc[ck*8];
      *(f32x4*)&hr[4] = *(const f32x4*)&hc[ck*8+4];
      aL += dot8(*(const uint4v*)&lw[(rl*32 + (ck ^ (rl & 31)))*8], hr);
    }
    parA[q4*256 + rl] = aL;
    // stream-part: half hf of row 256+rrh, depth-8 ring
    float aR = 0.f;
    const float* hh = hc + hf*128;
    #pragma unroll
    for (int q = 0; q < 16; ++q){
      float hr[8];
      *(f32x4*)&hr[0] = *(const f32x4*)&hh[q*8];
      *(f32x4*)&hr[4] = *(const f32x4*)&hh[q*8+4];
      aR += dot8(wb[q & 7], hr);
      wb[q & 7] = *(const uint4v*)(wsrc + (size_t)((q < 8) ? (q + 8) : (q - 8))*6144);
    }
    parB[hf*512 + rrh] = aR;
    __syncthreads();                   // B1: partials ready
    if (T < 256){
      const int j = T;
      const float A0 = parA[j] + parA[256+j] + parA[512+j] + parA[768+j] + bh0;
      const float A1 = parB[j] + parB[512+j] + bh1;
      const float A2 = parB[256+j] + parB[768+j] + bh2;
      const float r = sigmoidf_(g0 + A0);
      const float z = sigmoidf_(g1 + A1);
      const float n = tanhf(g2 + r*A2);
      const float hnew = (1.f - z)*n + z*hc[j];
      hn[j] = hnew;
      const size_t off = (size_t)(b*TEe + t)*512 + dir*256 + j;
      encoded[off] = hnew;
      encoded_bf[off] = f2bf(hnew);
    }
    __syncthreads();                   // B2: h_new visible
    const float* tmp = hc; hc = hn; hn = (float*)tmp;
  }
}

// ---------------- fused post: encb2 (blocks 0-1023) + sizes+hinit (1024-1055) ----------------
__global__ __launch_bounds__(256) void k_post(
  const float* __restrict__ encoded, const float* __restrict__ W2b, float* __restrict__ encb2,
  const int* __restrict__ enc_in, const float* __restrict__ W1w, const float* __restrict__ W1b,
  float* __restrict__ h0)
{
  if (blockIdx.x < 1024){
    // encb2[r] = encoded[r,:512] . W2_b   (4 rows/block, one wave per row)
    const int r = blockIdx.x*4 + (threadIdx.x >> 6), l = threadIdx.x & 63;
    const float* e = encoded + (size_t)r*512;
    float s = 0.f;
    for (int k = l; k < 512; k += 64) s += e[k]*W2b[k];
    for (int off = 32; off; off >>= 1) s += __shfl_down(s, off);
    if (l == 0) encb2[r] = s;
  } else {
    const int b = blockIdx.x - 1024, o = threadIdx.x;
    int c = 0;
    for (int t = 0; t < TEe; ++t) c += (enc_in[b*TEe + t] > 0);
    int idx = c - 1;
    idx = idx < 0 ? 0 : (idx > TEe-1 ? TEe-1 : idx);
    const float* ls = encoded + (size_t)(b*TEe + idx)*512;
    const float* wv = W1w + (size_t)o*512;
    float s = W1b[o];
    for (int k = 0; k < 512; k += 4){
      f32x4 a = *(const f32x4*)(ls + k);
      f32x4 w4 = *(const f32x4*)(wv + k);
      s = fmaf(a[0],w4[0], fmaf(a[1],w4[1], fmaf(a[2],w4[2], fmaf(a[3],w4[3], s))));
    }
    h0[b*256 + o] = s;
  }
}

// ---------------- decoder: 32 blocks = batch, 512 threads ----------------
// R12 version (unchanged, measured ~325us): 128-VGPR cap, persistent rings.
// n-gate: ctx (gc) stays OUTSIDE the r* product; bh_n INSIDE (ref semantics).
#define DLR 128
__global__ __launch_bounds__(512, 1) void k_decoder(
  const unsigned short* __restrict__ Whd, const float* __restrict__ bhd,
  const float* __restrict__ gidx,            // [B][TD][768] f32 (includes bi_d)
  const unsigned short* __restrict__ encw2,  // [B*TE][256] bf16
  const float* __restrict__ encb2,           // [B*TE]
  const unsigned short* __restrict__ projt,  // [B][16][768][8] bf16
  const float* __restrict__ h0,
  unsigned short* __restrict__ outs_bf)      // [B][TD][256] bf16
{
  extern __shared__ char smem[];
  unsigned short* le = (unsigned short*)smem;            // 65536
  unsigned short* lw = (unsigned short*)(smem + 65536);  // DLR*512 = 65536
  float* h    = (float*)(smem + 131072);                 // 1024
  float* parL = (float*)(smem + 132096);                 // 2048 (4 quarters x 128)
  float* parS1= (float*)(smem + 134144);                 // 2048 (rows 128-639)
  float* parS2= (float*)(smem + 136192);                 // 2048 (4 quarters x 128, rows 640-767)
  float* gcs  = (float*)(smem + 138240);                 // 2048 (ctx rows 0-511)
  float* cpar = (float*)(smem + 140288);                 // 2048 (2 halves x 256, ctx rows 512-767)
  float* p    = (float*)(smem + 142336);                 // 512
  float* ebl  = (float*)(smem + 142848);                 // 512 -> total 143360
  const int b = blockIdx.x, T = threadIdx.x;             // [0,512)
  const unsigned short* ptc = projt + (size_t)b*98304;
  const unsigned short* wsrcM = Whd + (size_t)(DLR + T)*8;     // rows 128..639
  const int trow = 640 + (T >> 2), tq = (T & 3)*8;             // rows 640..767
  const unsigned short* wsrcT = Whd + (size_t)trow*8;
  const unsigned short* csrcM = ptc + (size_t)T*8;             // ctx rows 0..511
  const int crow = 512 + (T >> 1), cq = (T & 1)*8;             // ctx rows 512..767
  const unsigned short* csrcT = ptc + (size_t)crow*8;
  uint4v wb[8], wb2[2], cb[4], cb2[2];
  #pragma unroll
  for (int d = 0; d < 8; ++d) wb[d] = *(const uint4v*)(wsrcM + (size_t)d*6144);
  wb2[0] = *(const uint4v*)(wsrcT + (size_t)tq*6144);
  wb2[1] = *(const uint4v*)(wsrcT + (size_t)(tq+1)*6144);
  #pragma unroll
  for (int d = 0; d < 4; ++d) cb[d] = *(const uint4v*)(csrcM + (size_t)d*6144);
  cb2[0] = *(const uint4v*)(csrcT + (size_t)cq*6144);
  cb2[1] = *(const uint4v*)(csrcT + (size_t)(cq+1)*6144);
  for (int cc = T; cc < 128*32; cc += 512){
    int r = cc >> 5, q = cc & 31;
    *(uint4v*)&le[(r*32 + (q ^ (r & 31)))*8] =
        *(const uint4v*)(encw2 + ((size_t)(b*TEe + r) << 8) + (q << 3));
  }
  for (int cc = T; cc < DLR*32; cc += 512){
    int r = cc >> 5, q = cc & 31;
    *(uint4v*)&lw[(r*32 + (q ^ (r & 31)))*8] =
        *(const uint4v*)(Whd + (size_t)q*6144 + r*8);
  }
  for (int i = T; i < 256; i += 512) h[i] = h0[b*256 + i];
  gcs[T] = 0.f; cpar[T] = 0.f;                           // ctx_init = 0
  if (T < TEe) ebl[T] = encb2[b*TEe + T];
  float bh0 = 0.f, bh1 = 0.f, bh2 = 0.f;
  if (T < 256){ bh0 = bhd[T]; bh1 = bhd[T+256]; bh2 = bhd[T+512]; }
  __syncthreads();
  float g0 = 0.f, g1 = 0.f, g2 = 0.f;
  if (T < 256){
    const float* grow = gidx + (size_t)(b*TDd)*768;
    g0 = grow[T]; g1 = grow[T+256]; g2 = grow[T+512];
  }
  #define DOTS_BODY                                                            \
  {                                                                            \
    { const int rL2 = T >> 2, qb2 = (T & 3)*8;                                 \
      const unsigned short* lwr = lw + rL2*256;                                \
      float a = 0.f;                                                           \
      _Pragma("unroll")                                                        \
      for (int i = 0; i < 8; ++i){                                             \
        const int q = qb2 + i;                                                 \
        float hr[8];                                                           \
        *(f32x4*)&hr[0] = *(const f32x4*)&h[q*8];                              \
        *(f32x4*)&hr[4] = *(const f32x4*)&h[q*8+4];                            \
        a += dot8(*(const uint4v*)(lwr + ((q ^ (rL2 & 31)) << 3)), hr);        \
      }                                                                        \
      parL[(T & 3)*128 + rL2] = a;                                             \
    }                                                                          \
    { float a = 0.f;                                                           \
      _Pragma("unroll")                                                        \
      for (int q = 0; q < 32; ++q){                                            \
        float hr[8];                                                           \
        *(f32x4*)&hr[0] = *(const f32x4*)&h[q*8];                              \
        *(f32x4*)&hr[4] = *(const f32x4*)&h[q*8+4];                            \
        a += dot8(wb[q & 7], hr);                                              \
        wb[q & 7] = *(const uint4v*)(wsrcM + (size_t)((q < 24) ? (q + 8) : (q - 24))*6144); \
      }                                                                        \
      parS1[T] = a;                                                            \
    }                                                                          \
    { float a = 0.f;                                                           \
      _Pragma("unroll")                                                        \
      for (int i = 0; i < 8; ++i){                                             \
        const int q = tq + i;                                                  \
        float hr[8];                                                           \
        *(f32x4*)&hr[0] = *(const f32x4*)&h[q*8];                              \
        *(f32x4*)&hr[4] = *(const f32x4*)&h[q*8+4];                            \
        a += dot8(wb2[i & 1], hr);                                             \
        wb2[i & 1] = *(const uint4v*)(wsrcT + (size_t)(tq + ((i < 6) ? (i + 2) : (i - 6)))*6144); \
      }                                                                        \
      parS2[(T & 3)*128 + (T >> 2)] = a;                                       \
    }                                                                          \
  }
  DOTS_BODY
  __syncthreads();
  for (int t = 0; t < TDd; ++t){
    if (T < 256){
      const int j = T;
      float A0, A2;
      if (j < 128){
        A0 = parL[j] + parL[128+j] + parL[256+j] + parL[384+j];
        A2 = parS1[384+j];
      } else {
        A0 = parS1[j-128];
        A2 = parS2[j-128] + parS2[j] + parS2[j+128] + parS2[j+256];
      }
      const float A1 = parS1[128+j];
      const float gcr = gcs[j];
      const float gcz = gcs[256+j];
      const float gcn = cpar[j] + cpar[256+j];
      const float r = sigmoidf_(g0 + gcr + A0 + bh0);
      const float z = sigmoidf_(g1 + gcz + A1 + bh1);
      const float n = tanhf(g2 + gcn + r*(A2 + bh2));
      const float hnew = (1.f - z)*n + z*h[j];
      h[j] = hnew;
      outs_bf[(size_t)(b*TDd + t)*256 + j] = f2bf(hnew);
    }
    if (t + 1 == TDd) break;
    __syncthreads();                   // B1: h_t visible
    if (T < 256){
      const float* grow = gidx + (size_t)(b*TDd + t + 1)*768;
      g0 = grow[T]; g1 = grow[T+256]; g2 = grow[T+512];
    }
    DOTS_BODY
    {
      const int pos = T >> 2, kq = (T & 3)*8;
      const unsigned short* er = le + pos*256;
      float s = 0.f;
      #pragma unroll
      for (int i = 0; i < 8; ++i){
        const int q = kq + i;
        float hr[8];
        *(f32x4*)&hr[0] = *(const f32x4*)&h[q*8];
        *(f32x4*)&hr[4] = *(const f32x4*)&h[q*8+4];
        s += dot8(*(const uint4v*)(er + ((q ^ (pos & 31)) << 3)), hr);
      }
      s += __shfl_xor(s, 1);
      s += __shfl_xor(s, 2);
      if ((T & 3) == 0) p[pos] = s + ebl[pos];
    }
    __syncthreads();                   // B2: raw scores ready
    if (T < 64){
      float m = fmaxf(p[T], p[T+64]);
      for (int off = 32; off; off >>= 1) m = fmaxf(m, __shfl_xor(m, off));
      float e0 = __expf(p[T] - m), e1 = __expf(p[T+64] - m);
      float ss = e0 + e1;
      for (int off = 32; off; off >>= 1) ss += __shfl_xor(ss, off);
      float inv = 1.f / ss;
      p[T] = e0*inv; p[T+64] = e1*inv;
    }
    __syncthreads();                   // B3: softmax done
    {
      float c = 0.f;
      #pragma unroll
      for (int q = 0; q < 16; ++q){
        float pr[8];
        *(f32x4*)&pr[0] = *(const f32x4*)&p[q*8];
        *(f32x4*)&pr[4] = *(const f32x4*)&p[q*8+4];
        c += dot8(cb[q & 3], pr);
        cb[q & 3] = *(const uint4v*)(csrcM + (size_t)((q < 12) ? (q + 4) : (q - 12))*6144);
      }
      gcs[T] = c;
      float c2 = 0.f;
      #pragma unroll
      for (int i = 0; i < 8; ++i){
        const int q = cq + i;
        float pr[8];
        *(f32x4*)&pr[0] = *(const f32x4*)&p[q*8];
        *(f32x4*)&pr[4] = *(const f32x4*)&p[q*8+4];
        c2 += dot8(cb2[i & 1], pr);
        cb2[i & 1] = *(const uint4v*)(csrcT + (size_t)(cq + ((i < 6) ? (i + 2) : (i - 6)))*6144);
      }
      cpar[(T & 1)*256 + (T >> 1)] = c2;
    }
    __syncthreads();                   // B4: gcs/cpar ready for next gates
  }
  #undef DOTS_BODY
}

extern "C" void kernel_launch(void* const* d_in, const int* in_sizes, int n_in,
                              void* d_out, int out_size, void* d_ws, size_t ws_size,
                              hipStream_t stream)
{
  (void)in_sizes; (void)n_in; (void)out_size;
  const int*   enc_in = (const int*)d_in[0];
  const int*   dec_in = (const int*)d_in[1];
  const float* embW   = (const float*)d_in[2];
  const float* Wi_f   = (const float*)d_in[3];
  const float* Wh_f   = (const float*)d_in[4];
  const float* bi_f   = (const float*)d_in[5];
  const float* bh_f   = (const float*)d_in[6];
  const float* Wi_b   = (const float*)d_in[7];
  const float* Wh_b   = (const float*)d_in[8];
  const float* bi_b   = (const float*)d_in[9];
  const float* bh_b   = (const float*)d_in[10];
  const float* Wi_d   = (const float*)d_in[11];
  const float* Wh_d   = (const float*)d_in[12];
  const float* bi_d   = (const float*)d_in[13];
  const float* bh_d   = (const float*)d_in[14];
  const float* W1_w   = (const float*)d_in[15];
  const float* W1_b   = (const float*)d_in[16];
  const float* W2_w   = (const float*)d_in[17];
  const float* W2_b   = (const float*)d_in[18];
  const float* lin_w  = (const float*)d_in[19];
  const float* lin_b  = (const float*)d_in[20];

  // d_out (262 MB) doubles as scratch; all regions dead before final GEMM.
  char* scr = (char*)d_out;
  float* gi_f    = (float*)(scr + 3145728);                     // 12,582,912
  float* gi_b    = (float*)(scr + 15728640);                    // 12,582,912
  float* gi_dx   = (float*)(scr + 28311552);                    //  6,291,456
  float* enc     = (float*)(scr + 34603008);                    //  8,388,608
  unsigned short* enc_bf  = (unsigned short*)(scr + 42991616);  //  4,194,304
  unsigned short* whf_bf = (unsigned short*)(scr + 53477376);   //    393,216
  unsigned short* whb_bf = (unsigned short*)(scr + 53870592);
  unsigned short* whd_bf = (unsigned short*)(scr + 54263808);
  unsigned short* encw2  = (unsigned short*)(scr + 54657024);   //  2,097,152
  unsigned short* projt  = (unsigned short*)(scr + 56754176);   //  6,291,456
  unsigned short* wif_bf = (unsigned short*)(scr + 63045632);   //    393,216
  unsigned short* wib_bf = (unsigned short*)(scr + 63438848);
  unsigned short* wid_bf = (unsigned short*)(scr + 63832064);   //  1,179,648
  unsigned short* w2t_bf = (unsigned short*)(scr + 65011712);   //    262,144
  float* encb2 = (float*)(scr + 65273856);
  float* h0    = (float*)(scr + 65290368);

  unsigned short* outs_bf = (unsigned short*)d_ws;
  unsigned short* lin_bf  = (unsigned short*)((char*)d_ws + (1<<20));
  const bool big = ws_size >= (size_t)(1<<20) + 16384000u + 1024u;

  hipFuncSetAttribute((const void*)k_encoder, hipFuncAttributeMaxDynamicSharedMemorySize, 141312);
  hipFuncSetAttribute((const void*)k_decoder, hipFuncAttributeMaxDynamicSharedMemorySize, 143360);

  // fused prep (weights -> chunked/bf16/transposed)
  k_prep<<<6656, 256, 0, stream>>>(Wh_f, Wh_b, Wh_d, Wi_f, Wi_b, Wi_d, W2_w,
                                   whf_bf, whb_bf, whd_bf, wif_bf, wib_bf, wid_bf, w2t_bf);

  // input projections with fused embedding gather
  k_gemm<false,true,true,0><<<dim3(6,32), 256, 0, stream>>>(
      nullptr, enc_in, embW, wif_bf, bi_f, gi_f, 4096, 768, 256, 0, 256, 768);
  k_gemm<false,true,true,0><<<dim3(6,32), 256, 0, stream>>>(
      nullptr, enc_in, embW, wib_bf, bi_b, gi_b, 4096, 768, 256, 0, 256, 768);
  k_gemm<false,true,true,0><<<dim3(6,16), 256, 0, stream>>>(
      nullptr, dec_in, embW, wid_bf + 512, bi_d, gi_dx, 2048, 768, 256, 0, 768, 768);

  // encoder recurrence + folded lin_w conversion on idle CUs
  k_encoder<<<192, 1024, 141312, stream>>>(whf_bf, whb_bf, bh_f, bh_b, gi_f, gi_b,
                                           enc, enc_bf, lin_w, lin_bf, big ? 1 : 0);
  // fused encb2 + sizes + hinit
  k_post<<<1056, 256, 0, stream>>>(enc, W2_b, encb2, enc_in, W1_w, W1_b, h0);

  // ENC_W2 = enc @ W2 (bf16 fast path via transposed W2)
  k_gemm<true,false,true,1><<<dim3(2,32), 256, 0, stream>>>(
      enc_bf, nullptr, nullptr, w2t_bf, nullptr, encw2, 4096, 256, 512, 512, 512, 256);
  // ENC_PROJ = enc @ Wi_ctx^T, written DIRECTLY in projt-chunked layout
  k_gemm<true,false,true,2><<<dim3(6,32), 256, 0, stream>>>(
      enc_bf, nullptr, nullptr, wid_bf, nullptr, projt, 4096, 768, 512, 512, 768, 0);

  k_decoder<<<Bb, 512, 143360, stream>>>(whd_bf, bh_d, gi_dx, encw2, encb2, projt, h0, outs_bf);

  if (big)
    k_gemm<true,false,true,0><<<dim3(250,16), 256, 0, stream>>>(
        outs_bf, nullptr, nullptr, lin_bf, lin_b, d_out, 2048, 32000, 256, 256, 256, 32000);
  else
    k_gemm<true,false,false,0><<<dim3(250,16), 256, 0, stream>>>(
        outs_bf, nullptr, nullptr, lin_w, lin_b, d_out, 2048, 32000, 256, 256, 256, 32000);
}